// Round 12
// baseline (509.499 us; speedup 1.0000x reference)
//
#include <hip/hip_runtime.h>

// 2-layer GCN, N=100000, E=1.6M, feat 128 -> 16 -> 128.
// P commutes with dense layers => aggregate in 16-wide hidden space.
// R3:  fp32 atomic scatter writes through to HBM (400MB/pass).
// R4/6: per-edge global atomics + random 4B stores -> ~60MB HBM writes.
// R7:  atomic-free bucket CSR build + fp16 hidden state (392->265us).
// R8:  gemm2 32 rows/block, W2 in regs (265->230us).
// R9:  fixed-capacity buckets kill bcount+bscan (230->207us).
// R10: CSR itself is overhead. Delete bcsr + both gathers: per-bucket LDS
//      scatter-accumulate (acc[256][17] fp32, ds_add_f32; stride-17 kills
//      bank conflicts), edges read once coalesced from pk. Layer-2 agg
//      fuses gemm2 in epilogue (no bufA, no col array at all).

#define THREADS 256
#define TSC 512               // bscatter/deg/agg block size
#define BSH 8                 // bucket shift: 256 nodes/bucket
#define BNODES 256
#define ECHUNK 4096           // edges per bscatter block
#define CAPB 4608             // slots/bucket (mean 4082, sd 64 -> +8.2 sigma)
#define NBMAX 512

typedef _Float16 half4 __attribute__((ext_vector_type(4)));

// ---- cursor[b] = b*CAPB ----
__global__ void k_init(int* __restrict__ cursor, int NB) {
    int i = blockIdx.x * blockDim.x + threadIdx.x;
    if (i < NB) cursor[i] = i * CAPB;
}

// ---- single-pass bucket scatter: stage+rank in LDS, atomic-free write ----
__global__ void __launch_bounds__(TSC) k_bscatter(
        const int* __restrict__ src, const int* __restrict__ dst,
        int* __restrict__ cursor, int* __restrict__ pk, int NB, int E) {
    __shared__ int eds[ECHUNK];             // packed (dloc<<17)|src
    __shared__ int rb[ECHUNK];              // (bucket<<13)|rank
    __shared__ int h[NBMAX];
    __shared__ int lbase[NBMAX];
    int tid = threadIdx.x;
    int base0 = blockIdx.x * ECHUNK, end = min(base0 + ECHUNK, E);
    int cnt = end - base0;
    for (int i = tid; i < NB; i += TSC) h[i] = 0;
    __syncthreads();
    int k0 = base0 + tid * 8;
    if (k0 + 8 <= end) {                    // vector path: 2x int4 per array
        int4 d0 = *reinterpret_cast<const int4*>(dst + k0);
        int4 d1 = *reinterpret_cast<const int4*>(dst + k0 + 4);
        int4 s0 = *reinterpret_cast<const int4*>(src + k0);
        int4 s1 = *reinterpret_cast<const int4*>(src + k0 + 4);
        int dd[8] = {d0.x, d0.y, d0.z, d0.w, d1.x, d1.y, d1.z, d1.w};
        int ss[8] = {s0.x, s0.y, s0.z, s0.w, s1.x, s1.y, s1.z, s1.w};
        int j0 = k0 - base0;
#pragma unroll
        for (int j = 0; j < 8; ++j) {
            int b = dd[j] >> BSH;
            int r = atomicAdd(&h[b], 1);    // rank assigned at count time
            eds[j0 + j] = ((dd[j] & (BNODES - 1)) << 17) | ss[j];
            rb[j0 + j] = (b << 13) | r;     // r < 8192 always (<= ECHUNK)
        }
    } else if (k0 < end) {
        for (int k = k0; k < end; ++k) {
            int d = dst[k], s = src[k];
            int b = d >> BSH;
            int r = atomicAdd(&h[b], 1);
            int j = k - base0;
            eds[j] = ((d & (BNODES - 1)) << 17) | s;
            rb[j] = (b << 13) | r;
        }
    }
    __syncthreads();
    for (int i = tid; i < NB; i += TSC)
        lbase[i] = h[i] ? atomicAdd(&cursor[i], h[i]) : 0;
    __syncthreads();
    for (int j = tid; j < cnt; j += TSC) {  // atomic-free write phase
        int v = rb[j];
        pk[lbase[v >> 13] + (v & 8191)] = eds[j];
    }
}

// ---- per-bucket degree -> dinv (LDS histogram over pk segment) ----
__global__ void __launch_bounds__(TSC) k_deg(
        const int* __restrict__ pk, const int* __restrict__ cursor,
        float* __restrict__ dinv, int N) {
    __shared__ int deg[BNODES];
    int b = blockIdx.x, tid = threadIdx.x;
    int base = b * CAPB;
    int len = min(cursor[b] - base, CAPB);
    if (tid < BNODES) deg[tid] = 0;
    __syncthreads();
    for (int k = tid; k < len; k += TSC) atomicAdd(&deg[pk[base + k] >> 17], 1);
    __syncthreads();
    int node = (b << BSH) + tid;
    if (tid < BNODES && node < N) dinv[node] = rsqrtf((float)(deg[tid] + 1));
}

// ---- hs[N,16] = (x@W1)*dinv, stored fp16 (3.2MB: XCD-L2-resident) ----
__global__ void k_gemm1(const float* __restrict__ x, const float* __restrict__ W1,
                        const float* __restrict__ dinv, _Float16* __restrict__ hs, int n) {
    __shared__ float w[128 * 16];
    __shared__ float xs[16][129];
    int tid = threadIdx.x;
    for (int i = tid; i < 128 * 16; i += THREADS) w[i] = W1[i];
    int brow = blockIdx.x * 16;
    {
        int r = tid >> 4, off = (tid & 15) * 8;
        if (brow + r < n) {
            const float* xr = x + (size_t)(brow + r) * 128 + off;
            float4 a = *reinterpret_cast<const float4*>(xr);
            float4 b = *reinterpret_cast<const float4*>(xr + 4);
            xs[r][off + 0] = a.x; xs[r][off + 1] = a.y; xs[r][off + 2] = a.z; xs[r][off + 3] = a.w;
            xs[r][off + 4] = b.x; xs[r][off + 5] = b.y; xs[r][off + 6] = b.z; xs[r][off + 7] = b.w;
        }
    }
    __syncthreads();
    int r = tid >> 4, c = tid & 15;
    int row = brow + r;
    if (row >= n) return;
    float acc = 0.0f;
#pragma unroll 8
    for (int k = 0; k < 128; ++k) acc = fmaf(xs[r][k], w[k * 16 + c], acc);
    hs[(size_t)row * 16 + c] = (_Float16)(acc * dinv[row]);
}

// ---- per-bucket LDS scatter-accumulate (replaces CSR + gather) ----
// acc[dloc][f] += hin[src][f] over the bucket's edges; self-term via init.
// LAYER 1: h1s[node] = (half)(relu(dinv*acc + b1) * dinv)
// LAYER 2: out[node,:] = (dinv*acc) @ W2 + b2   (fused gemm2 epilogue)
template <int LAYER>
__global__ void __launch_bounds__(TSC) k_agg(
        const _Float16* __restrict__ hin, const float* __restrict__ dinv,
        const int* __restrict__ pk, const int* __restrict__ cursor,
        const float* __restrict__ bias, const float* __restrict__ W2,
        _Float16* __restrict__ out_h, float* __restrict__ out_f, int N) {
    __shared__ float acc[BNODES][17];       // stride 17: conflict-free random rows
    int b = blockIdx.x, tid = threadIdx.x;
    int base = b * CAPB;
    int len = min(cursor[b] - base, CAPB);
    int node0 = (b << BSH) + tid;           // valid only for tid < BNODES
    if (tid < BNODES) {
        if (node0 < N) {                    // self-loop term
            const _Float16* hp = hin + (size_t)node0 * 16;
#pragma unroll
            for (int f = 0; f < 16; f += 4) {
                half4 v = *reinterpret_cast<const half4*>(hp + f);
                acc[tid][f + 0] = (float)v.x; acc[tid][f + 1] = (float)v.y;
                acc[tid][f + 2] = (float)v.z; acc[tid][f + 3] = (float)v.w;
            }
        } else {
#pragma unroll
            for (int f = 0; f < 16; ++f) acc[tid][f] = 0.0f;
        }
    }
    __syncthreads();
    // edge accumulate: 4 lanes per edge, half4 read, 4x ds_add_f32
    int q = (tid & 3) * 4;
#pragma unroll 2
    for (int e = (tid >> 2); e < len; e += (TSC / 4)) {
        int p = pk[base + e];
        int d = p >> 17;                    // dloc < 256
        int s = p & 0x1FFFF;
        half4 v = *reinterpret_cast<const half4*>(hin + (size_t)s * 16 + q);
        atomicAdd(&acc[d][q + 0], (float)v.x);
        atomicAdd(&acc[d][q + 1], (float)v.y);
        atomicAdd(&acc[d][q + 2], (float)v.z);
        atomicAdd(&acc[d][q + 3], (float)v.w);
    }
    __syncthreads();
    if (LAYER == 1) {
        if (tid < BNODES && node0 < N) {
            float dv = dinv[node0];
            alignas(16) _Float16 tmp[16];
#pragma unroll
            for (int f = 0; f < 16; ++f)
                tmp[f] = (_Float16)(fmaxf(fmaf(dv, acc[tid][f], bias[f]), 0.0f) * dv);
            float4* dp = reinterpret_cast<float4*>(out_h + (size_t)node0 * 16);
            const float4* sp = reinterpret_cast<const float4*>(tmp);
            dp[0] = sp[0]; dp[1] = sp[1];
        }
    } else {
        if (tid < BNODES && node0 < N) {    // scale rows by dinv in LDS
            float dv = dinv[node0];
#pragma unroll
            for (int f = 0; f < 16; ++f) acc[tid][f] *= dv;
        }
        __syncthreads();
        int col = tid & 127, grp = tid >> 7;  // 4 groups x 64 nodes
        float w[16];
#pragma unroll
        for (int k = 0; k < 16; ++k) w[k] = W2[k * 128 + col];
        float bb = bias[col];
        for (int rr = 0; rr < BNODES / 4; ++rr) {
            int r = grp * (BNODES / 4) + rr;
            int node = (b << BSH) + r;
            if (node >= N) break;
            float s = bb;
#pragma unroll
            for (int k = 0; k < 16; ++k) s = fmaf(acc[r][k], w[k], s);
            out_f[(size_t)node * 128 + col] = s;
        }
    }
}

extern "C" void kernel_launch(void* const* d_in, const int* in_sizes, int n_in,
                              void* d_out, int out_size, void* d_ws, size_t ws_size,
                              hipStream_t stream) {
    const float* x  = (const float*)d_in[0];
    const int*   ei = (const int*)d_in[1];
    const float* W1 = (const float*)d_in[2];
    const float* b1 = (const float*)d_in[3];
    const float* W2 = (const float*)d_in[4];
    const float* b2 = (const float*)d_in[5];
    float* out = (float*)d_out;

    int N = in_sizes[0] / 128;
    int E = in_sizes[1] / 2;
    const int* src = ei;
    const int* dst = ei + E;
    int NB = (N + BNODES - 1) >> BSH;       // 391 buckets
    int EB = (E + ECHUNK - 1) / ECHUNK;     // 391 scatter blocks
    size_t PADSZ = (size_t)NB * CAPB;       // 1.80M slots

    char* ws = (char*)d_ws;
    size_t o = 0;
    auto carve = [&](size_t bytes) { void* p = ws + o; o = (o + bytes + 255) & ~(size_t)255; return p; };
    int*      cursor = (int*)carve((size_t)NB * 4);
    int*      pk     = (int*)carve(PADSZ * 4);                 // packed (dloc,src)
    float*    dinv   = (float*)carve((size_t)N * 4);
    _Float16* hs     = (_Float16*)carve((size_t)N * 16 * 2);   // fp16 hidden (3.2MB)
    _Float16* h1s    = (_Float16*)carve((size_t)N * 16 * 2);

    // build: bucket scatter + degrees (no CSR, no per-edge global atomics)
    k_init<<<(NB + THREADS - 1) / THREADS, THREADS, 0, stream>>>(cursor, NB);
    k_bscatter<<<EB, TSC, 0, stream>>>(src, dst, cursor, pk, NB, E);
    k_deg<<<NB, TSC, 0, stream>>>(pk, cursor, dinv, N);

    // layer 1: hs = (x@W1)*dinv ; h1s = relu(dinv*agg(hs) + b1)*dinv
    k_gemm1<<<(N + 15) / 16, THREADS, 0, stream>>>(x, W1, dinv, hs, N);
    k_agg<1><<<NB, TSC, 0, stream>>>(hs, dinv, pk, cursor, b1, nullptr, h1s, nullptr, N);

    // layer 2: out = (dinv*agg(h1s)) @ W2 + b2   (gemm2 fused in epilogue)
    k_agg<2><<<NB, TSC, 0, stream>>>(h1s, dinv, pk, cursor, b2, W2, nullptr, out, N);
}

// Round 13
// 209.123 us; speedup vs baseline: 2.4364x; 2.4364x over previous
//
#include <hip/hip_runtime.h>

// 2-layer GCN, N=100000, E=1.6M, feat 128 -> 16 -> 128.
// P commutes with dense layers => aggregate in 16-wide hidden space.
// R3:  fp32 atomic scatter writes through to HBM (400MB/pass).
// R4/6: per-edge global atomics + random 4B stores -> ~60MB HBM writes.
// R7:  atomic-free bucket CSR build + fp16 hidden state (392->265us).
// R8:  gemm2 32 rows/block, W2 in regs (265->230us).
// R9:  fixed-capacity buckets kill bcount+bscan (230->207us).
// R10/12: LDS fp32 atomicAdd = CAS loop in this harness (no unsafe-fp-atomics)
//      -> 509us REGRESSION. Reverted. Int LDS atomics only.
// R12: (a) bcsr occupancy: 256-node buckets -> 391 blocks (was 196 @ 0.77/CU);
//      (b) gemm2 fused into gather2 epilogue via LDS rows (exclusive writes,
//      no atomics) -> bufA round trip + 1 launch gone.

#define THREADS 256
#define TSC 512               // bscatter/bcsr block size
#define BSH 8                 // bucket shift: 256 nodes/bucket
#define BNODES 256
#define ECHUNK 4096           // edges per bscatter block
#define CAPB 4608             // slots/bucket (mean 4092, sd ~64 -> +8 sigma)
#define NBMAX 512

typedef _Float16 half4 __attribute__((ext_vector_type(4)));

// ---- cursor[b] = b*CAPB ----
__global__ void k_init(int* __restrict__ cursor, int NB) {
    int i = blockIdx.x * blockDim.x + threadIdx.x;
    if (i < NB) cursor[i] = i * CAPB;
}

// ---- single-pass bucket scatter: stage+rank in LDS, atomic-free write ----
__global__ void __launch_bounds__(TSC) k_bscatter(
        const int* __restrict__ src, const int* __restrict__ dst,
        int* __restrict__ cursor, int* __restrict__ pk, int NB, int E) {
    __shared__ int eds[ECHUNK];             // packed (dloc<<17)|src
    __shared__ int rb[ECHUNK];              // (bucket<<13)|rank
    __shared__ int h[NBMAX];
    __shared__ int lbase[NBMAX];
    int tid = threadIdx.x;
    int base0 = blockIdx.x * ECHUNK, end = min(base0 + ECHUNK, E);
    int cnt = end - base0;
    for (int i = tid; i < NB; i += TSC) h[i] = 0;
    __syncthreads();
    int k0 = base0 + tid * 8;
    if (k0 + 8 <= end) {                    // vector path: 2x int4 per array
        int4 d0 = *reinterpret_cast<const int4*>(dst + k0);
        int4 d1 = *reinterpret_cast<const int4*>(dst + k0 + 4);
        int4 s0 = *reinterpret_cast<const int4*>(src + k0);
        int4 s1 = *reinterpret_cast<const int4*>(src + k0 + 4);
        int dd[8] = {d0.x, d0.y, d0.z, d0.w, d1.x, d1.y, d1.z, d1.w};
        int ss[8] = {s0.x, s0.y, s0.z, s0.w, s1.x, s1.y, s1.z, s1.w};
        int j0 = k0 - base0;
#pragma unroll
        for (int j = 0; j < 8; ++j) {
            int b = dd[j] >> BSH;
            int r = atomicAdd(&h[b], 1);    // int LDS atomic: native ds_add
            eds[j0 + j] = ((dd[j] & (BNODES - 1)) << 17) | ss[j];
            rb[j0 + j] = (b << 13) | r;     // r < 8192 always (<= ECHUNK)
        }
    } else if (k0 < end) {
        for (int k = k0; k < end; ++k) {
            int d = dst[k], s = src[k];
            int b = d >> BSH;
            int r = atomicAdd(&h[b], 1);
            int j = k - base0;
            eds[j] = ((d & (BNODES - 1)) << 17) | s;
            rb[j] = (b << 13) | r;
        }
    }
    __syncthreads();
    for (int i = tid; i < NB; i += TSC)
        lbase[i] = h[i] ? atomicAdd(&cursor[i], h[i]) : 0;
    __syncthreads();
    for (int j = tid; j < cnt; j += TSC) {  // atomic-free write phase
        int v = rb[j];
        pk[lbase[v >> 13] + (v & 8191)] = eds[j];
    }
}

// ---- per-bucket exact CSR + dinv, all in LDS (256 nodes, 391 blocks) ----
__global__ void __launch_bounds__(TSC) k_bcsr(
        const int* __restrict__ pk, const int* __restrict__ cursor,
        int* __restrict__ row_ptr, int* __restrict__ row_cnt,
        float* __restrict__ dinv, int* __restrict__ col, int N) {
    __shared__ int eds[CAPB];               // 18KB
    __shared__ int deg[BNODES], sc[BNODES], cur[BNODES];
    int b = blockIdx.x, tid = threadIdx.x;
    int base = b * CAPB;
    int len = min(cursor[b] - base, CAPB);
    for (int k = tid; k < len; k += TSC) eds[k] = pk[base + k];
    if (tid < BNODES) deg[tid] = 0;
    __syncthreads();
    for (int k = tid; k < len; k += TSC) atomicAdd(&deg[eds[k] >> 17], 1);
    __syncthreads();
    int d = (tid < BNODES) ? deg[tid] : 0;
    if (tid < BNODES) sc[tid] = d;
    __syncthreads();
    for (int off = 1; off < BNODES; off <<= 1) {
        int t = (tid < BNODES && tid >= off) ? sc[tid - off] : 0;
        __syncthreads();
        if (tid < BNODES) sc[tid] += t;
        __syncthreads();
    }
    if (tid < BNODES) {
        int excl = sc[tid] - d;
        cur[tid] = excl;
        int node = (b << BSH) + tid;
        if (node < N) {
            row_ptr[node] = base + excl;
            row_cnt[node] = d;
            dinv[node] = rsqrtf((float)(d + 1));
        }
    }
    __syncthreads();
    for (int k = tid; k < len; k += TSC) {
        int p = eds[k];
        int r = atomicAdd(&cur[p >> 17], 1);  // int LDS rank
        col[base + r] = p & 0x1FFFF;          // writes stay in 18KB window
    }
}

// ---- hs[N,16] = (x@W1)*dinv, stored fp16 (3.2MB: XCD-L2-resident) ----
__global__ void k_gemm1(const float* __restrict__ x, const float* __restrict__ W1,
                        const float* __restrict__ dinv, _Float16* __restrict__ hs, int n) {
    __shared__ float w[128 * 16];
    __shared__ float xs[16][129];
    int tid = threadIdx.x;
    for (int i = tid; i < 128 * 16; i += THREADS) w[i] = W1[i];
    int brow = blockIdx.x * 16;
    {
        int r = tid >> 4, off = (tid & 15) * 8;
        if (brow + r < n) {
            const float* xr = x + (size_t)(brow + r) * 128 + off;
            float4 a = *reinterpret_cast<const float4*>(xr);
            float4 b = *reinterpret_cast<const float4*>(xr + 4);
            xs[r][off + 0] = a.x; xs[r][off + 1] = a.y; xs[r][off + 2] = a.z; xs[r][off + 3] = a.w;
            xs[r][off + 4] = b.x; xs[r][off + 5] = b.y; xs[r][off + 6] = b.z; xs[r][off + 7] = b.w;
        }
    }
    __syncthreads();
    int r = tid >> 4, c = tid & 15;
    int row = brow + r;
    if (row >= n) return;
    float acc = 0.0f;
#pragma unroll 8
    for (int k = 0; k < 128; ++k) acc = fmaf(xs[r][k], w[k * 16 + c], acc);
    hs[(size_t)row * 16 + c] = (_Float16)(acc * dinv[row]);
}

// ---- layer-1 gather over padded CSR; fp16 in/out, 4-deep unroll ----
__global__ void k_gather1(const _Float16* __restrict__ hin, const float* __restrict__ dinv,
                          const int* __restrict__ row_ptr, const int* __restrict__ row_cnt,
                          const int* __restrict__ col, const float* __restrict__ bias,
                          _Float16* __restrict__ out_h, int n) {
    int gid = blockIdx.x * blockDim.x + threadIdx.x;  // n*4 threads
    if (gid >= n * 4) return;
    int node = gid >> 2, q = (gid & 3) * 4;
    int s0 = row_ptr[node], s1 = s0 + row_cnt[node];
    half4 hv = *reinterpret_cast<const half4*>(hin + (size_t)node * 16 + q);
    float ax = (float)hv.x, ay = (float)hv.y, az = (float)hv.z, aw = (float)hv.w;
    int k = s0;
    for (; k + 3 < s1; k += 4) {
        int c0 = col[k], c1 = col[k + 1], c2 = col[k + 2], c3 = col[k + 3];
        half4 v0 = *reinterpret_cast<const half4*>(hin + (size_t)c0 * 16 + q);
        half4 v1 = *reinterpret_cast<const half4*>(hin + (size_t)c1 * 16 + q);
        half4 v2 = *reinterpret_cast<const half4*>(hin + (size_t)c2 * 16 + q);
        half4 v3 = *reinterpret_cast<const half4*>(hin + (size_t)c3 * 16 + q);
        ax += (float)v0.x + (float)v1.x + (float)v2.x + (float)v3.x;
        ay += (float)v0.y + (float)v1.y + (float)v2.y + (float)v3.y;
        az += (float)v0.z + (float)v1.z + (float)v2.z + (float)v3.z;
        aw += (float)v0.w + (float)v1.w + (float)v2.w + (float)v3.w;
    }
    for (; k < s1; ++k) {
        half4 v = *reinterpret_cast<const half4*>(hin + (size_t)col[k] * 16 + q);
        ax += (float)v.x; ay += (float)v.y; az += (float)v.z; aw += (float)v.w;
    }
    float dv = dinv[node];
    float4 b = *reinterpret_cast<const float4*>(bias + q);
    half4 o;
    o.x = (_Float16)(fmaxf(fmaf(dv, ax, b.x), 0.0f) * dv);
    o.y = (_Float16)(fmaxf(fmaf(dv, ay, b.y), 0.0f) * dv);
    o.z = (_Float16)(fmaxf(fmaf(dv, az, b.z), 0.0f) * dv);
    o.w = (_Float16)(fmaxf(fmaf(dv, aw, b.w), 0.0f) * dv);
    *reinterpret_cast<half4*>(out_h + (size_t)node * 16 + q) = o;
}

// ---- layer-2 gather + fused gemm2: 64 nodes/block ----
// phase 1: 4 thr/node gather -> rows[64][17] in LDS (exclusive writes, no atomics)
// phase 2: out[node,:] = rows @ W2 + b2, W2 col in regs, coalesced stores
__global__ void __launch_bounds__(THREADS) k_gather2f(
        const _Float16* __restrict__ hin, const float* __restrict__ dinv,
        const int* __restrict__ row_ptr, const int* __restrict__ row_cnt,
        const int* __restrict__ col, const float* __restrict__ W2,
        const float* __restrict__ b2, float* __restrict__ out, int n) {
    __shared__ float rows[64][17];          // stride 17: conflict-free
    int tid = threadIdx.x;
    int bnode = blockIdx.x * 64;
    {   // phase 1: gather
        int nloc = tid >> 2, q = (tid & 3) * 4;
        int node = bnode + nloc;
        if (node < n) {
            int s0 = row_ptr[node], s1 = s0 + row_cnt[node];
            half4 hv = *reinterpret_cast<const half4*>(hin + (size_t)node * 16 + q);
            float ax = (float)hv.x, ay = (float)hv.y, az = (float)hv.z, aw = (float)hv.w;
            int k = s0;
            for (; k + 3 < s1; k += 4) {
                int c0 = col[k], c1 = col[k + 1], c2 = col[k + 2], c3 = col[k + 3];
                half4 v0 = *reinterpret_cast<const half4*>(hin + (size_t)c0 * 16 + q);
                half4 v1 = *reinterpret_cast<const half4*>(hin + (size_t)c1 * 16 + q);
                half4 v2 = *reinterpret_cast<const half4*>(hin + (size_t)c2 * 16 + q);
                half4 v3 = *reinterpret_cast<const half4*>(hin + (size_t)c3 * 16 + q);
                ax += (float)v0.x + (float)v1.x + (float)v2.x + (float)v3.x;
                ay += (float)v0.y + (float)v1.y + (float)v2.y + (float)v3.y;
                az += (float)v0.z + (float)v1.z + (float)v2.z + (float)v3.z;
                aw += (float)v0.w + (float)v1.w + (float)v2.w + (float)v3.w;
            }
            for (; k < s1; ++k) {
                half4 v = *reinterpret_cast<const half4*>(hin + (size_t)col[k] * 16 + q);
                ax += (float)v.x; ay += (float)v.y; az += (float)v.z; aw += (float)v.w;
            }
            float dv = dinv[node];
            rows[nloc][q + 0] = ax * dv;
            rows[nloc][q + 1] = ay * dv;
            rows[nloc][q + 2] = az * dv;
            rows[nloc][q + 3] = aw * dv;
        }
    }
    __syncthreads();
    {   // phase 2: fused gemm2
        int c = tid & 127, grp = tid >> 7;  // 2 groups x 32 rows
        float w[16];
#pragma unroll
        for (int k = 0; k < 16; ++k) w[k] = W2[k * 128 + c];
        float bb = b2[c];
        for (int rr = 0; rr < 32; ++rr) {
            int r = grp * 32 + rr;
            int node = bnode + r;
            if (node >= n) break;
            float s = bb;
#pragma unroll
            for (int k = 0; k < 16; ++k) s = fmaf(rows[r][k], w[k], s);
            out[(size_t)node * 128 + c] = s;
        }
    }
}

extern "C" void kernel_launch(void* const* d_in, const int* in_sizes, int n_in,
                              void* d_out, int out_size, void* d_ws, size_t ws_size,
                              hipStream_t stream) {
    const float* x  = (const float*)d_in[0];
    const int*   ei = (const int*)d_in[1];
    const float* W1 = (const float*)d_in[2];
    const float* b1 = (const float*)d_in[3];
    const float* W2 = (const float*)d_in[4];
    const float* b2 = (const float*)d_in[5];
    float* out = (float*)d_out;

    int N = in_sizes[0] / 128;
    int E = in_sizes[1] / 2;
    const int* src = ei;
    const int* dst = ei + E;
    int NB = (N + BNODES - 1) >> BSH;       // 391 buckets
    int EB = (E + ECHUNK - 1) / ECHUNK;     // 391 scatter blocks
    size_t PADSZ = (size_t)NB * CAPB;       // 1.80M slots

    char* ws = (char*)d_ws;
    size_t o = 0;
    auto carve = [&](size_t bytes) { void* p = ws + o; o = (o + bytes + 255) & ~(size_t)255; return p; };
    int*      cursor  = (int*)carve((size_t)NB * 4);
    int*      pk      = (int*)carve(PADSZ * 4);                // packed (dloc,src)
    int*      col     = (int*)carve(PADSZ * 4);                // CSR col (padded)
    int*      row_ptr = (int*)carve((size_t)N * 4);
    int*      row_cnt = (int*)carve((size_t)N * 4);
    float*    dinv    = (float*)carve((size_t)N * 4);
    _Float16* hs      = (_Float16*)carve((size_t)N * 16 * 2);  // fp16 hidden (3.2MB)
    _Float16* h1s     = (_Float16*)carve((size_t)N * 16 * 2);

    int gN4 = (N * 4 + THREADS - 1) / THREADS;

    // CSR build: fixed-capacity buckets, int-only LDS atomics
    k_init<<<(NB + THREADS - 1) / THREADS, THREADS, 0, stream>>>(cursor, NB);
    k_bscatter<<<EB, TSC, 0, stream>>>(src, dst, cursor, pk, NB, E);
    k_bcsr<<<NB, TSC, 0, stream>>>(pk, cursor, row_ptr, row_cnt, dinv, col, N);

    // layer 1: hs = (x@W1)*dinv ; h1s = relu(dinv*gather(hs) + b1)*dinv
    k_gemm1<<<(N + 15) / 16, THREADS, 0, stream>>>(x, W1, dinv, hs, N);
    k_gather1<<<gN4, THREADS, 0, stream>>>(hs, dinv, row_ptr, row_cnt, col, b1, h1s, N);

    // layer 2: out = (dinv*gather(h1s)) @ W2 + b2  (gemm2 fused, no bufA)
    k_gather2f<<<(N + 63) / 64, THREADS, 0, stream>>>(h1s, dinv, row_ptr, row_cnt, col, W2, b2, out, N);
}